// Round 1
// baseline (452.909 us; speedup 1.0000x reference)
//
#include <hip/hip_runtime.h>
#include <hip/hip_bf16.h>
#include <stdint.h>

// Problem shape (fixed by the reference): out[M,N] = x[M,K] @ (base + coeff*(2*mask-1))[K,N]
#define M_DIM 8192
#define K_DIM 4096
#define N_DIM 4096

typedef __attribute__((ext_vector_type(8))) short short8;
typedef __attribute__((ext_vector_type(4))) float f32x4;

typedef const __attribute__((address_space(1))) unsigned int as1const_u32;
typedef __attribute__((address_space(3))) unsigned int as3_u32;

__device__ __forceinline__ unsigned short f2bf(float f) {
  unsigned int u = __float_as_uint(f);
  u += 0x7FFF + ((u >> 16) & 1);   // round-to-nearest-even
  return (unsigned short)(u >> 16);
}

// ---------- prep 1: x (f32) -> bf16, vectorized 8 elems/thread/iter ----------
__global__ void cvt_x_kernel(const float* __restrict__ x,
                             unsigned short* __restrict__ xb, long n8) {
  long i = (long)blockIdx.x * blockDim.x + threadIdx.x;
  long stride = (long)gridDim.x * blockDim.x;
  for (; i < n8; i += stride) {
    const float4* p = (const float4*)(x + i * 8);
    float4 v0 = p[0], v1 = p[1];
    short8 o;
    o[0] = (short)f2bf(v0.x); o[1] = (short)f2bf(v0.y);
    o[2] = (short)f2bf(v0.z); o[3] = (short)f2bf(v0.w);
    o[4] = (short)f2bf(v1.x); o[5] = (short)f2bf(v1.y);
    o[6] = (short)f2bf(v1.z); o[7] = (short)f2bf(v1.w);
    *(short8*)(xb + i * 8) = o;
  }
}

// ---------- prep 2: Wt[n][k] = bf16(base[k][n] + coeff*(2*mask[k][n]-1)) ----------
// 32x32 LDS tile transpose, coalesced on both global sides.
__global__ void make_wt_kernel(const float* __restrict__ base,
                               const int* __restrict__ mask,
                               const float* __restrict__ coeffp,
                               unsigned short* __restrict__ wt) {
  __shared__ unsigned short tile[32][33];
  const float c = *coeffp;
  const int n0 = blockIdx.x * 32, k0 = blockIdx.y * 32;
  const int tx = threadIdx.x, ty = threadIdx.y;
#pragma unroll
  for (int r = 0; r < 4; ++r) {
    int k = k0 + ty + r * 8;
    int n = n0 + tx;
    size_t idx = (size_t)k * N_DIM + n;
    float s = mask[idx] ? c : -c;
    tile[ty + r * 8][tx] = f2bf(base[idx] + s);
  }
  __syncthreads();
#pragma unroll
  for (int r = 0; r < 4; ++r) {
    int n = n0 + ty + r * 8;
    int k = k0 + tx;
    wt[(size_t)n * K_DIM + k] = tile[tx][ty + r * 8];
  }
}

// ---------- main GEMM: out[M,N] = Xb[M,K](bf16) * Wt[N,K](bf16)^T, f32 out ----------
// m97 structure: 128x128 tile, BK=32, 4 waves (2x2), global_load_lds width 16,
// 16x16x32 bf16 MFMA, 4x4 fragments/wave. LDS swizzle: chunk j ^= (row>>1)&3
// applied on the *global source* (rule 21: linear DMA dest) and on the read.
__global__ __launch_bounds__(256) void gemm_bf16_kernel(
    const unsigned short* __restrict__ Xb,
    const unsigned short* __restrict__ Wt,
    float* __restrict__ out) {
  __shared__ unsigned short As[128 * 32];
  __shared__ unsigned short Bs[128 * 32];

  const int tid = threadIdx.x;
  const int lane = tid & 63;
  const int w = tid >> 6;           // wave id 0..3
  const int wm = w >> 1, wn = w & 1;
  const int bm = blockIdx.y * 128, bn = blockIdx.x * 128;
  const int lrow = lane & 15;       // row within 16x16 fragment
  const int kg = lane >> 4;         // k-group 0..3 (8 contiguous k each)

  f32x4 acc[4][4] = {};

  // staging chunks: 512 chunks of 16B per operand tile; thread t owns c and c+256.
  // LDS chunk (row, j) holds global k8-chunk j ^ ((row>>1)&3)  (bank-uniform reads)
  const int c0 = tid, c1 = 256 + tid;
  const int row0 = c0 >> 2, j0 = c0 & 3;
  const int row1 = c1 >> 2, j1 = c1 & 3;
  const int k80 = (j0 ^ ((row0 >> 1) & 3)) * 8;
  const int k81 = (j1 ^ ((row1 >> 1) & 3)) * 8;
  const unsigned short* gA0 = Xb + (size_t)(bm + row0) * K_DIM + k80;
  const unsigned short* gA1 = Xb + (size_t)(bm + row1) * K_DIM + k81;
  const unsigned short* gB0 = Wt + (size_t)(bn + row0) * K_DIM + k80;
  const unsigned short* gB1 = Wt + (size_t)(bn + row1) * K_DIM + k81;
  // wave-uniform LDS bases (dest = base + lane*16)
  char* lA0 = (char*)As + w * 1024;
  char* lA1 = (char*)As + 4096 + w * 1024;
  char* lB0 = (char*)Bs + w * 1024;
  char* lB1 = (char*)Bs + 4096 + w * 1024;

  const int swz = (kg ^ ((lrow >> 1) & 3)) << 4;  // byte offset of lane's 16B chunk

  for (int kt = 0; kt < K_DIM; kt += 32) {
    __builtin_amdgcn_global_load_lds((as1const_u32*)(gA0 + kt), (as3_u32*)lA0, 16, 0, 0);
    __builtin_amdgcn_global_load_lds((as1const_u32*)(gA1 + kt), (as3_u32*)lA1, 16, 0, 0);
    __builtin_amdgcn_global_load_lds((as1const_u32*)(gB0 + kt), (as3_u32*)lB0, 16, 0, 0);
    __builtin_amdgcn_global_load_lds((as1const_u32*)(gB1 + kt), (as3_u32*)lB1, 16, 0, 0);
    __syncthreads();  // drains vmcnt(0): tiles ready

    short8 a[4], b[4];
#pragma unroll
    for (int mi = 0; mi < 4; ++mi) {
      int row = wm * 64 + mi * 16 + lrow;
      a[mi] = *(const short8*)((const char*)As + row * 64 + swz);
    }
#pragma unroll
    for (int ni = 0; ni < 4; ++ni) {
      int row = wn * 64 + ni * 16 + lrow;
      b[ni] = *(const short8*)((const char*)Bs + row * 64 + swz);
    }
#pragma unroll
    for (int mi = 0; mi < 4; ++mi)
#pragma unroll
      for (int ni = 0; ni < 4; ++ni)
        acc[mi][ni] = __builtin_amdgcn_mfma_f32_16x16x32_bf16(a[mi], b[ni], acc[mi][ni], 0, 0, 0);
    __syncthreads();  // protect LDS before next tile's DMA
  }

  // epilogue: C/D layout col=lane&15, row=(lane>>4)*4+reg  [m89/m91]
#pragma unroll
  for (int mi = 0; mi < 4; ++mi) {
#pragma unroll
    for (int ni = 0; ni < 4; ++ni) {
      int gr = bm + wm * 64 + mi * 16 + kg * 4;
      int gc = bn + wn * 64 + ni * 16 + lrow;
      float* o = out + (size_t)gr * N_DIM + gc;
#pragma unroll
      for (int r = 0; r < 4; ++r)
        o[(size_t)r * N_DIM] = acc[mi][ni][r];
    }
  }
}

// ---------- fallback (only if workspace is too small): exact f32 tiled GEMM ----------
__global__ void gemm_f32_fallback(const float* __restrict__ x,
                                  const float* __restrict__ base,
                                  const float* __restrict__ coeffp,
                                  const int* __restrict__ mask,
                                  float* __restrict__ out) {
  __shared__ float As[32][33];
  __shared__ float Bs[32][33];
  const float c = *coeffp;
  const int tx = threadIdx.x, ty = threadIdx.y;
  const int row = blockIdx.y * 32 + ty, col = blockIdx.x * 32 + tx;
  float acc = 0.f;
  for (int kt = 0; kt < K_DIM; kt += 32) {
    As[ty][tx] = x[(size_t)row * K_DIM + kt + tx];
    size_t bidx = (size_t)(kt + ty) * N_DIM + col;
    Bs[ty][tx] = base[bidx] + (mask[bidx] ? c : -c);
    __syncthreads();
#pragma unroll
    for (int k = 0; k < 32; ++k) acc += As[ty][k] * Bs[k][tx];
    __syncthreads();
  }
  out[(size_t)row * N_DIM + col] = acc;
}

extern "C" void kernel_launch(void* const* d_in, const int* in_sizes, int n_in,
                              void* d_out, int out_size, void* d_ws, size_t ws_size,
                              hipStream_t stream) {
  const float* x     = (const float*)d_in[0];
  const float* base  = (const float*)d_in[1];
  const float* coeff = (const float*)d_in[2];
  const int*   mask  = (const int*)d_in[3];
  float* out = (float*)d_out;

  const size_t xb_bytes = (size_t)M_DIM * K_DIM * sizeof(unsigned short);  // 64 MiB
  const size_t wt_bytes = (size_t)K_DIM * N_DIM * sizeof(unsigned short);  // 32 MiB

  if (ws_size >= xb_bytes + wt_bytes) {
    unsigned short* xb = (unsigned short*)d_ws;
    unsigned short* wt = (unsigned short*)((char*)d_ws + xb_bytes);
    long n8 = (long)M_DIM * K_DIM / 8;
    cvt_x_kernel<<<4096, 256, 0, stream>>>(x, xb, n8);
    make_wt_kernel<<<dim3(N_DIM / 32, K_DIM / 32), dim3(32, 8), 0, stream>>>(base, mask, coeff, wt);
    gemm_bf16_kernel<<<dim3(N_DIM / 128, M_DIM / 128), 256, 0, stream>>>(xb, wt, out);
  } else {
    gemm_f32_fallback<<<dim3(N_DIM / 32, M_DIM / 32), dim3(32, 32), 0, stream>>>(x, base, coeff, mask, out);
  }
}

// Round 3
// 302.679 us; speedup vs baseline: 1.4963x; 1.4963x over previous
//
#include <hip/hip_runtime.h>
#include <hip/hip_bf16.h>
#include <stdint.h>

// out[M,N] = x[M,K] @ (base + coeff*(2*mask-1))[K,N]
#define M_DIM 8192
#define K_DIM 4096
#define N_DIM 4096
#define NT (K_DIM / 64)   // 64 K-tiles of BK=64

typedef __attribute__((ext_vector_type(8))) short short8;
typedef __attribute__((ext_vector_type(4))) float f32x4;
typedef unsigned short ushort_t;

typedef const __attribute__((address_space(1))) unsigned int as1const_u32;
typedef __attribute__((address_space(3))) unsigned int as3_u32;

__device__ __forceinline__ unsigned short f2bf(float f) {
  unsigned int u = __float_as_uint(f);
  u += 0x7FFF + ((u >> 16) & 1);   // round-to-nearest-even
  return (unsigned short)(u >> 16);
}

// ---------- prep 1: x (f32) -> bf16, vectorized ----------
__global__ void cvt_x_kernel(const float* __restrict__ x,
                             ushort_t* __restrict__ xb, long n8) {
  long i = (long)blockIdx.x * blockDim.x + threadIdx.x;
  long stride = (long)gridDim.x * blockDim.x;
  for (; i < n8; i += stride) {
    const float4* p = (const float4*)(x + i * 8);
    float4 v0 = p[0], v1 = p[1];
    short8 o;
    o[0] = (short)f2bf(v0.x); o[1] = (short)f2bf(v0.y);
    o[2] = (short)f2bf(v0.z); o[3] = (short)f2bf(v0.w);
    o[4] = (short)f2bf(v1.x); o[5] = (short)f2bf(v1.y);
    o[6] = (short)f2bf(v1.z); o[7] = (short)f2bf(v1.w);
    *(short8*)(xb + i * 8) = o;
  }
}

// ---------- prep 2: Wt[n][k] = bf16(base[k][n] + coeff*sign) ----------
__global__ void make_wt_kernel(const float* __restrict__ base,
                               const int* __restrict__ mask,
                               const float* __restrict__ coeffp,
                               ushort_t* __restrict__ wt) {
  __shared__ ushort_t tile[32][33];
  const float c = *coeffp;
  const int n0 = blockIdx.x * 32, k0 = blockIdx.y * 32;
  const int tx = threadIdx.x, ty = threadIdx.y;
#pragma unroll
  for (int r = 0; r < 4; ++r) {
    int k = k0 + ty + r * 8;
    int n = n0 + tx;
    size_t idx = (size_t)k * N_DIM + n;
    float s = mask[idx] ? c : -c;
    tile[ty + r * 8][tx] = f2bf(base[idx] + s);
  }
  __syncthreads();
#pragma unroll
  for (int r = 0; r < 4; ++r) {
    int n = n0 + ty + r * 8;
    int k = k0 + tx;
    wt[(size_t)n * K_DIM + k] = tile[tx][ty + r * 8];
  }
}

// ---------- 256x256 deep-pipelined bf16 GEMM (4-phase, counted vmcnt) ----------
// Stage stream (2 loads each): p1:(t+1,B,h1) p2:(t+1,A,h1) p3:(t+2,A,h0) p4:(t+2,B,h0).
// vmcnt(6) at p1/p2/p4 gives every read-dependence >=1 stage of slack (re-derived).
// TAIL FIX (round-2 bug): loop runs t < NT-1 (all counted stages real); then a
// vmcnt(0)+barrier drain and a peeled, stage-free last K-tile. Previously the
// skipped u>=NT stages made the tail vmcnt(8) a no-op -> last-tile race.
#define FENCE asm volatile("" ::: "memory")
#define BAR   do { FENCE; __builtin_amdgcn_s_barrier(); FENCE; } while (0)
#define VW6   asm volatile("s_waitcnt vmcnt(6)" ::: "memory")
#define VW0   asm volatile("s_waitcnt vmcnt(0)" ::: "memory")

__global__ __launch_bounds__(512, 2) void gemm_bf16_256(
    const ushort_t* __restrict__ Xb,
    const ushort_t* __restrict__ Wt,
    float* __restrict__ out) {
  __shared__ ushort_t Al[2][256][64];   // 64 KiB
  __shared__ ushort_t Bl[2][256][64];   // 64 KiB

  const int tid = threadIdx.x;
  const int lane = tid & 63;
  const int w = tid >> 6;               // wave 0..7
  const int wm = w >> 2, wn = w & 3;    // 2M x 4N
  const int lrow = lane & 15, kg = lane >> 4;

  // T1: bijective XCD swizzle (512 % 8 == 0)
  const int bid = blockIdx.x;
  const int swz = (bid & 7) * 64 + (bid >> 3);
  const int bm = (swz >> 4) * 256;      // 0..31 * 256
  const int bn = (swz & 15) * 256;      // 0..15 * 256

  // staging: thread (w,lane) covers half-row rh0 = w*8+(lane>>3) (+64 on load 2),
  // LDS slot lane&7; source chunk = slot ^ (row&7) (pre-swizzled source; the
  // ds_read applies the same XOR -> both-sides swizzle, rule 21).
  const int rh0 = w * 8 + (lane >> 3);
  const int srcslot = (lane & 7) ^ ((lane >> 3) & 7);
  const ushort_t* Ag = Xb + (size_t)(bm + rh0) * K_DIM + srcslot * 8;
  const ushort_t* Bg = Wt + (size_t)(bn + rh0) * K_DIM + srcslot * 8;
  char* AlB = (char*)&Al[0][0][0];
  char* BlB = (char*)&Bl[0][0][0];
  const int ldsw = w * 1024;

#define STAGE(Og, Lb, u, h) do { if ((u) < NT) {                                   \
    const ushort_t* _s0 = (Og) + (size_t)((h) * 128) * K_DIM + (size_t)(u) * 64;   \
    __builtin_amdgcn_global_load_lds((as1const_u32*)_s0,                           \
        (as3_u32*)((Lb) + ((u) & 1) * 32768 + (h) * 16384 + ldsw), 16, 0, 0);      \
    __builtin_amdgcn_global_load_lds((as1const_u32*)(_s0 + (size_t)64 * K_DIM),    \
        (as3_u32*)((Lb) + ((u) & 1) * 32768 + (h) * 16384 + ldsw + 8192), 16, 0, 0); \
  } } while (0)

  // LDS read addresses (byte): row*128 + ((kk*4+kg)^(lrow&7))*16
  const int arow = (wm * 16 + lrow) << 7;
  const int brow = (wn * 16 + lrow) << 7;
  const int sw0 = ((0 + kg) ^ (lrow & 7)) << 4;
  const int sw1 = ((4 + kg) ^ (lrow & 7)) << 4;

#define LDA(bt, mi, kk) (*(const short8*)(AlB + (bt) * 32768 + (mi) * 4096 + arow + ((kk) ? sw1 : sw0)))
#define LDB(bt, ni, kk) (*(const short8*)(BlB + (bt) * 32768 + (ni) * 8192 + brow + ((kk) ? sw1 : sw0)))
#define MFMA(a, b, c) __builtin_amdgcn_mfma_f32_16x16x32_bf16(a, b, c, 0, 0, 0)

  f32x4 acc[8][4] = {};
  short8 Ar[4][2], Br[4][2];

  // prologue: tile 0 all 4 halves + tile 1 h0 halves; vmcnt(6) -> first 3 stages
  // landed = (0,A,h0),(0,B,h0),(0,B,h1)
  STAGE(Ag, AlB, 0, 0); STAGE(Bg, BlB, 0, 0);
  STAGE(Bg, BlB, 0, 1); STAGE(Ag, AlB, 0, 1);
  STAGE(Ag, AlB, 1, 0); STAGE(Bg, BlB, 1, 0);
  VW6; BAR;

  for (int t = 0; t < NT - 1; ++t) {
    const int bt = t & 1;

    // ---- phase 1: read Ah0(mi0-3) + Bh0(ni0-1); stage (t+1,B,h1); MFMA (lo,lo) ----
#pragma unroll
    for (int mi = 0; mi < 4; ++mi) { Ar[mi][0] = LDA(bt, mi, 0); Ar[mi][1] = LDA(bt, mi, 1); }
#pragma unroll
    for (int ni = 0; ni < 2; ++ni) { Br[ni][0] = LDB(bt, ni, 0); Br[ni][1] = LDB(bt, ni, 1); }
    STAGE(Bg, BlB, t + 1, 1);
    BAR;
    __builtin_amdgcn_s_setprio(1);
#pragma unroll
    for (int mi = 0; mi < 4; ++mi)
#pragma unroll
      for (int ni = 0; ni < 2; ++ni) {
        acc[mi][ni] = MFMA(Ar[mi][0], Br[ni][0], acc[mi][ni]);
        acc[mi][ni] = MFMA(Ar[mi][1], Br[ni][1], acc[mi][ni]);
      }
    __builtin_amdgcn_s_setprio(0);
    VW6; BAR;

    // ---- phase 2: read Bh1(ni2-3); stage (t+1,A,h1); MFMA (lo,hi) ----
#pragma unroll
    for (int ni = 2; ni < 4; ++ni) { Br[ni][0] = LDB(bt, ni, 0); Br[ni][1] = LDB(bt, ni, 1); }
    STAGE(Ag, AlB, t + 1, 1);
    BAR;
    __builtin_amdgcn_s_setprio(1);
#pragma unroll
    for (int mi = 0; mi < 4; ++mi)
#pragma unroll
      for (int ni = 2; ni < 4; ++ni) {
        acc[mi][ni] = MFMA(Ar[mi][0], Br[ni][0], acc[mi][ni]);
        acc[mi][ni] = MFMA(Ar[mi][1], Br[ni][1], acc[mi][ni]);
      }
    __builtin_amdgcn_s_setprio(0);
    VW6; BAR;

    // ---- phase 3: read Ah1(mi4-7); stage (t+2,A,h0); MFMA (hi,lo) ----
#pragma unroll
    for (int mi = 0; mi < 4; ++mi) { Ar[mi][0] = LDA(bt, mi + 4, 0); Ar[mi][1] = LDA(bt, mi + 4, 1); }
    STAGE(Ag, AlB, t + 2, 0);
    BAR;
    __builtin_amdgcn_s_setprio(1);
#pragma unroll
    for (int mi = 0; mi < 4; ++mi)
#pragma unroll
      for (int ni = 0; ni < 2; ++ni) {
        acc[mi + 4][ni] = MFMA(Ar[mi][0], Br[ni][0], acc[mi + 4][ni]);
        acc[mi + 4][ni] = MFMA(Ar[mi][1], Br[ni][1], acc[mi + 4][ni]);
      }
    __builtin_amdgcn_s_setprio(0);
    BAR;   // no vmcnt: phase 4 reads nothing from LDS

    // ---- phase 4: stage (t+2,B,h0); MFMA (hi,hi) ----
    STAGE(Bg, BlB, t + 2, 0);
    BAR;
    __builtin_amdgcn_s_setprio(1);
#pragma unroll
    for (int mi = 0; mi < 4; ++mi)
#pragma unroll
      for (int ni = 2; ni < 4; ++ni) {
        acc[mi + 4][ni] = MFMA(Ar[mi][0], Br[ni][0], acc[mi + 4][ni]);
        acc[mi + 4][ni] = MFMA(Ar[mi][1], Br[ni][1], acc[mi + 4][ni]);
      }
    __builtin_amdgcn_s_setprio(0);
    VW6; BAR;
  }

  // ---- peeled last K-tile: drain ALL DMA, then stage-free compute ----
  VW0; BAR;
  {
    const int bt = (NT - 1) & 1;
#pragma unroll
    for (int mi = 0; mi < 4; ++mi) { Ar[mi][0] = LDA(bt, mi, 0); Ar[mi][1] = LDA(bt, mi, 1); }
#pragma unroll
    for (int ni = 0; ni < 4; ++ni) { Br[ni][0] = LDB(bt, ni, 0); Br[ni][1] = LDB(bt, ni, 1); }
#pragma unroll
    for (int mi = 0; mi < 4; ++mi)
#pragma unroll
      for (int ni = 0; ni < 4; ++ni) {
        acc[mi][ni] = MFMA(Ar[mi][0], Br[ni][0], acc[mi][ni]);
        acc[mi][ni] = MFMA(Ar[mi][1], Br[ni][1], acc[mi][ni]);
      }
#pragma unroll
    for (int mi = 0; mi < 4; ++mi) { Ar[mi][0] = LDA(bt, mi + 4, 0); Ar[mi][1] = LDA(bt, mi + 4, 1); }
#pragma unroll
    for (int mi = 0; mi < 4; ++mi)
#pragma unroll
      for (int ni = 0; ni < 4; ++ni) {
        acc[mi + 4][ni] = MFMA(Ar[mi][0], Br[ni][0], acc[mi + 4][ni]);
        acc[mi + 4][ni] = MFMA(Ar[mi][1], Br[ni][1], acc[mi + 4][ni]);
      }
  }

  // epilogue: C/D layout col=lane&15, row=(lane>>4)*4+r  [m89/m91]
#pragma unroll
  for (int mi = 0; mi < 8; ++mi)
#pragma unroll
    for (int ni = 0; ni < 4; ++ni) {
      const int gr = bm + mi * 32 + wm * 16 + kg * 4;
      const int gc = bn + ni * 64 + wn * 16 + lrow;
      float* o = out + (size_t)gr * N_DIM + gc;
#pragma unroll
      for (int r = 0; r < 4; ++r) o[(size_t)r * N_DIM] = acc[mi][ni][r];
    }
}

// ---------- fallback (tiny workspace): exact f32 tiled GEMM ----------
__global__ void gemm_f32_fallback(const float* __restrict__ x,
                                  const float* __restrict__ base,
                                  const float* __restrict__ coeffp,
                                  const int* __restrict__ mask,
                                  float* __restrict__ out) {
  __shared__ float As[32][33];
  __shared__ float Bs[32][33];
  const float c = *coeffp;
  const int tx = threadIdx.x, ty = threadIdx.y;
  const int row = blockIdx.y * 32 + ty, col = blockIdx.x * 32 + tx;
  float acc = 0.f;
  for (int kt = 0; kt < K_DIM; kt += 32) {
    As[ty][tx] = x[(size_t)row * K_DIM + kt + tx];
    size_t bidx = (size_t)(kt + ty) * N_DIM + col;
    Bs[ty][tx] = base[bidx] + (mask[bidx] ? c : -c);
    __syncthreads();
#pragma unroll
    for (int k = 0; k < 32; ++k) acc += As[ty][k] * Bs[k][tx];
    __syncthreads();
  }
  out[(size_t)row * N_DIM + col] = acc;
}

extern "C" void kernel_launch(void* const* d_in, const int* in_sizes, int n_in,
                              void* d_out, int out_size, void* d_ws, size_t ws_size,
                              hipStream_t stream) {
  const float* x     = (const float*)d_in[0];
  const float* base  = (const float*)d_in[1];
  const float* coeff = (const float*)d_in[2];
  const int*   mask  = (const int*)d_in[3];
  float* out = (float*)d_out;

  const size_t xb_bytes = (size_t)M_DIM * K_DIM * sizeof(ushort_t);  // 64 MiB
  const size_t wt_bytes = (size_t)K_DIM * N_DIM * sizeof(ushort_t);  // 32 MiB

  if (ws_size >= xb_bytes + wt_bytes) {
    ushort_t* xb = (ushort_t*)d_ws;
    ushort_t* wt = (ushort_t*)((char*)d_ws + xb_bytes);
    long n8 = (long)M_DIM * K_DIM / 8;
    cvt_x_kernel<<<4096, 256, 0, stream>>>(x, xb, n8);
    make_wt_kernel<<<dim3(N_DIM / 32, K_DIM / 32), dim3(32, 8), 0, stream>>>(base, mask, coeff, wt);
    gemm_bf16_256<<<512, 512, 0, stream>>>(xb, wt, out);
  } else {
    gemm_f32_fallback<<<dim3(N_DIM / 32, M_DIM / 32), dim3(32, 32), 0, stream>>>(x, base, coeff, mask, out);
  }
}